// Round 1
// baseline (1676.201 us; speedup 1.0000x reference)
//
#include <hip/hip_runtime.h>
#include <hip/hip_bf16.h>

// Shapes: B=4, S=4096, E=2048, NH=16, HD=128.  ST = B*S = 16384 rows.
// qkv buffer layout: [16384][6144] bf16, cols 0..2047=q, 2048..4095=k, 4096..6143=v.

typedef __attribute__((ext_vector_type(4))) float  f32x4;
typedef __attribute__((ext_vector_type(8))) short  s16x8;

__device__ __forceinline__ unsigned short f2bf(float f) {
  unsigned u = __float_as_uint(f);
  unsigned r = (u + 0x7FFFu + ((u >> 16) & 1u)) >> 16;   // RNE
  return (unsigned short)r;
}
__device__ __forceinline__ float bf2f(unsigned short u) {
  return __uint_as_float(((unsigned)u) << 16);
}

// async global->LDS, 16B per lane. LDS dest must be wave-uniform base + lane*16.
__device__ __forceinline__ void gld16(const void* g, void* l) {
  __builtin_amdgcn_global_load_lds(
      (const __attribute__((address_space(1))) unsigned int*)g,
      (__attribute__((address_space(3))) unsigned int*)l,
      16, 0, 0);
}

// ---------------------------------------------------------------- prep kernels
__global__ void cast_x_kernel(const float* __restrict__ x,
                              unsigned short* __restrict__ xb, long n) {
  long i = ((long)blockIdx.x * blockDim.x + threadIdx.x) * 4;
  if (i < n) {
    float4 v = *(const float4*)(x + i);
    ushort4 o;
    o.x = f2bf(v.x); o.y = f2bf(v.y); o.z = f2bf(v.z); o.w = f2bf(v.w);
    *(ushort4*)(xb + i) = o;
  }
}

// Wt[n][k] = W[k][n] as bf16. z picks Wq/Wk/Wv -> wqkv_t rows z*2048.., z=3 -> wfc_t.
__global__ void transw_kernel(const float* __restrict__ Wq, const float* __restrict__ Wk,
                              const float* __restrict__ Wv, const float* __restrict__ Wfc,
                              unsigned short* __restrict__ wqkv_t,
                              unsigned short* __restrict__ wfc_t) {
  __shared__ float tile[32][33];
  int z = blockIdx.z;
  const float* W = (z == 0) ? Wq : (z == 1) ? Wk : (z == 2) ? Wv : Wfc;
  unsigned short* dst = (z < 3) ? (wqkv_t + (size_t)z * 2048 * 2048) : wfc_t;
  int x0 = blockIdx.x * 32, y0 = blockIdx.y * 32;
  int tx = threadIdx.x & 31, ty = threadIdx.x >> 5;  // 256 thr: ty 0..7
#pragma unroll
  for (int r = 0; r < 4; ++r)
    tile[ty + r * 8][tx] = W[(size_t)(y0 + ty + r * 8) * 2048 + x0 + tx];
  __syncthreads();
#pragma unroll
  for (int r = 0; r < 4; ++r)
    dst[(size_t)(x0 + ty + r * 8) * 2048 + y0 + tx] = f2bf(tile[tx][ty + r * 8]);
}

__global__ void bias_kernel(const float* __restrict__ bq, const float* __restrict__ bk,
                            const float* __restrict__ bv, float* __restrict__ bqkv) {
  int i = blockIdx.x * 256 + threadIdx.x;  // 6144
  bqkv[i] = (i < 2048) ? bq[i] : (i < 4096) ? bk[i - 2048] : bv[i - 4096];
}

// ---------------------------------------------------------------- main GEMM
// C[M,N] = A[M,K] * B^T[N,K] (+bias). 128x128 tile, BK=64, 256 thr, 4 waves (2x2),
// each wave 4x4 tiles of 16x16x32 bf16 MFMA. A,B staged via global_load_lds x16B.
// Batched via grid.z: z -> (zb = z/nhmod, zh = z%nhmod) offsets.
template <bool OUT_BF16, bool HAS_BIAS>
__global__ __launch_bounds__(256, 2)
void gemm_bt(const unsigned short* __restrict__ A, int lda,
             const unsigned short* __restrict__ B, int ldb,
             const float* __restrict__ bias,
             void* __restrict__ C, int ldc, int K,
             long sAb, long sAh, long sBb, long sBh, long sCb, long sCh,
             int nhmod) {
  __shared__ __align__(16) unsigned short As[128 * 64];
  __shared__ __align__(16) unsigned short Bs[128 * 64];
  const int t = threadIdx.x;
  const int lane = t & 63;
  const int w = t >> 6;
  const int wr = (w >> 1) * 64, wc = (w & 1) * 64;
  const int l15 = lane & 15, lq = lane >> 4;
  const int zb = blockIdx.z / nhmod, zh = blockIdx.z - zb * nhmod;
  const unsigned short* Ab = A + zb * sAb + zh * sAh + (size_t)blockIdx.y * 128 * lda;
  const unsigned short* Bb = B + zb * sBb + zh * sBh + (size_t)blockIdx.x * 128 * ldb;

  f32x4 acc[4][4] = {};
  const int nk = K >> 6;
  const int srow = t >> 3, scol = (t & 7) * 8;  // staging chunk: row srow+32i, col scol

  for (int kt = 0; kt < nk; ++kt) {
    const unsigned short* Ag = Ab + kt * 64 + (size_t)srow * lda + scol;
    const unsigned short* Bg = Bb + kt * 64 + (size_t)srow * ldb + scol;
    __syncthreads();
#pragma unroll
    for (int i = 0; i < 4; ++i) {
      gld16(Ag + (size_t)(32 * i) * lda, As + t * 8 + i * 2048);
      gld16(Bg + (size_t)(32 * i) * ldb, Bs + t * 8 + i * 2048);
    }
    __syncthreads();
#pragma unroll
    for (int ks = 0; ks < 2; ++ks) {
      s16x8 af[4], bf[4];
#pragma unroll
      for (int i = 0; i < 4; ++i) {
        af[i] = *(const s16x8*)(As + (wr + i * 16 + l15) * 64 + ks * 32 + lq * 8);
        bf[i] = *(const s16x8*)(Bs + (wc + i * 16 + l15) * 64 + ks * 32 + lq * 8);
      }
#pragma unroll
      for (int i = 0; i < 4; ++i)
#pragma unroll
        for (int j = 0; j < 4; ++j)
          acc[i][j] = __builtin_amdgcn_mfma_f32_16x16x32_bf16(af[i], bf[j], acc[i][j], 0, 0, 0);
    }
  }
  // epilogue: D[m = quad*4+r][n = lane&15]
  const long Cbase = zb * sCb + zh * sCh;
  const long row0 = (long)blockIdx.y * 128 + wr + lq * 4;
  const long col0 = (long)blockIdx.x * 128 + wc + l15;
#pragma unroll
  for (int j = 0; j < 4; ++j) {
    long col = col0 + j * 16;
    float bv = HAS_BIAS ? bias[col] : 0.0f;
#pragma unroll
    for (int i = 0; i < 4; ++i)
#pragma unroll
      for (int r = 0; r < 4; ++r) {
        float v = acc[i][j][r] + bv;
        long idx = Cbase + (row0 + i * 16 + r) * (long)ldc + col;
        if (OUT_BF16) ((unsigned short*)C)[idx] = f2bf(v);
        else          ((float*)C)[idx] = v;
      }
  }
}

// ---------------------------------------------------------------- K^T K, K^T V
// grid (64 heads, 8 s-chunks of 512). fp32 outer-product accumulate, atomicAdd out.
__global__ __launch_bounds__(256, 2)
void kkktv_kernel(const unsigned short* __restrict__ qkv,
                  float* __restrict__ kk, float* __restrict__ ktv) {
  __shared__ __align__(16) unsigned short kl[16 * 128];
  __shared__ __align__(16) unsigned short vl[16 * 128];
  const int bh = blockIdx.x;
  const int b = bh >> 4, h = bh & 15;
  const int t = threadIdx.x;
  const int ty = t >> 4, tx = t & 15;
  const unsigned short* kbase = qkv + (size_t)b * 4096 * 6144 + 2048 + h * 128;
  float akk[8][8] = {};
  float atv[8][8] = {};
  const int s0 = blockIdx.y * 512;
  const int sr = t >> 4, sc = (t & 15) * 8;

  for (int sb = 0; sb < 32; ++sb) {
    const unsigned short* kg = kbase + (size_t)(s0 + sb * 16 + sr) * 6144 + sc;
    __syncthreads();
    gld16(kg, kl + t * 8);
    gld16(kg + 2048, vl + t * 8);  // v is 2048 cols after k
    __syncthreads();
#pragma unroll 4
    for (int s = 0; s < 16; ++s) {
      const unsigned short* kr = kl + s * 128;
      s16x8 a8 = *(const s16x8*)(kr + ty * 8);
      s16x8 b8 = *(const s16x8*)(kr + tx * 8);
      s16x8 v8 = *(const s16x8*)(vl + s * 128 + tx * 8);
      float a[8], bb[8], vv[8];
#pragma unroll
      for (int i = 0; i < 8; ++i) {
        a[i]  = bf2f((unsigned short)a8[i]);
        bb[i] = bf2f((unsigned short)b8[i]);
        vv[i] = bf2f((unsigned short)v8[i]);
      }
#pragma unroll
      for (int i = 0; i < 8; ++i)
#pragma unroll
        for (int j = 0; j < 8; ++j) {
          akk[i][j] = fmaf(a[i], bb[j], akk[i][j]);
          atv[i][j] = fmaf(a[i], vv[j], atv[i][j]);
        }
    }
  }
  float* kkb = kk + (size_t)bh * 16384;
  float* tvb = ktv + (size_t)bh * 16384;
#pragma unroll
  for (int i = 0; i < 8; ++i)
#pragma unroll
    for (int j = 0; j < 8; ++j) {
      atomicAdd(&kkb[(ty * 8 + i) * 128 + tx * 8 + j], akk[i][j]);
      atomicAdd(&tvb[(ty * 8 + i) * 128 + tx * 8 + j], atv[i][j]);
    }
}

// ------------------------------------------- inverse(alpha I + K^TK) @ K^TV, softmax
// One block per head. In-LDS Gauss-Jordan (no pivoting: SPD, cond~2), then product
// with ktv (global, L1-resident), softmax over last dim, store transposed bf16:
// score_t[e*128 + d] = softmax(X)[d][e]  (B^T layout for the q@score GEMM).
__global__ __launch_bounds__(256, 1)
void inv_softmax_kernel(const float* __restrict__ kk, const float* __restrict__ ktv,
                        const float* __restrict__ alphap,
                        unsigned short* __restrict__ score_t) {
  __shared__ __align__(16) float A[128 * 132];     // row stride 132 floats
  __shared__ __align__(16) float rowbuf[2][132];
  __shared__ __align__(16) float colbuf[2][132];
  const int bh = blockIdx.x, t = threadIdx.x;
  const float* kkb = kk + (size_t)bh * 16384;
  const float* tvb = ktv + (size_t)bh * 16384;
  const float al = alphap[0];

  for (int i = t; i < 16384; i += 256) {
    int r = i >> 7, c = i & 127;
    A[r * 132 + c] = kkb[i] + ((r == c) ? al : 0.0f);
  }
  __syncthreads();
  if (t < 128) { rowbuf[0][t] = A[t]; colbuf[0][t] = A[t * 132]; }
  __syncthreads();

  const int i2 = t >> 1, half = t & 1;
  const int jb = half * 64;
  for (int k = 0; k < 128; ++k) {
    const float* rb = rowbuf[k & 1];
    float piv = rb[k];
    float d = 1.0f / piv;
    float c = colbuf[k & 1][i2];
    bool isPivRow = (i2 == k);
    float cd = isPivRow ? 0.0f : c * d;
    float scale = isPivRow ? d : 1.0f;
    float* Arow = A + i2 * 132 + jb;
    const float* rbh = rb + jb;
#pragma unroll
    for (int jj = 0; jj < 16; ++jj) {
      float4 r4 = *(const float4*)(rbh + jj * 4);
      float4 v = *(float4*)(Arow + jj * 4);
      v.x = v.x * scale - cd * r4.x;
      v.y = v.y * scale - cd * r4.y;
      v.z = v.z * scale - cd * r4.z;
      v.w = v.w * scale - cd * r4.w;
      *(float4*)(Arow + jj * 4) = v;
    }
    // fixes done by the thread owning column k (same thread that wrote that chunk)
    if ((k >> 6) == half) {
      if (!isPivRow) A[i2 * 132 + k] = -c * d;
      else           A[k * 132 + k] = d;
    }
    __syncthreads();
    if (t < 128 && k < 127) {
      rowbuf[(k + 1) & 1][t] = A[(k + 1) * 132 + t];
      colbuf[(k + 1) & 1][t] = A[t * 132 + (k + 1)];
    }
    __syncthreads();
  }

  // X = Ainv @ ktv : thread (ty2,tx2) computes 8x8 tile
  const int ty2 = t >> 4, tx2 = t & 15;
  float X[8][8] = {};
  for (int f = 0; f < 128; ++f) {
    float av[8];
#pragma unroll
    for (int i = 0; i < 8; ++i) av[i] = A[(ty2 * 8 + i) * 132 + f];
    float4 b0 = *(const float4*)(tvb + f * 128 + tx2 * 8);
    float4 b1 = *(const float4*)(tvb + f * 128 + tx2 * 8 + 4);
#pragma unroll
    for (int i = 0; i < 8; ++i) {
      X[i][0] = fmaf(av[i], b0.x, X[i][0]); X[i][1] = fmaf(av[i], b0.y, X[i][1]);
      X[i][2] = fmaf(av[i], b0.z, X[i][2]); X[i][3] = fmaf(av[i], b0.w, X[i][3]);
      X[i][4] = fmaf(av[i], b1.x, X[i][4]); X[i][5] = fmaf(av[i], b1.y, X[i][5]);
      X[i][6] = fmaf(av[i], b1.z, X[i][6]); X[i][7] = fmaf(av[i], b1.w, X[i][7]);
    }
  }
  __syncthreads();
#pragma unroll
  for (int i = 0; i < 8; ++i) {
    *(float4*)(A + (ty2 * 8 + i) * 132 + tx2 * 8)     = make_float4(X[i][0], X[i][1], X[i][2], X[i][3]);
    *(float4*)(A + (ty2 * 8 + i) * 132 + tx2 * 8 + 4) = make_float4(X[i][4], X[i][5], X[i][6], X[i][7]);
  }
  __syncthreads();
  // softmax over e (cols); thread pair (row r, half) ; store transposed bf16
  {
    const int r = t >> 1;
    const float* row = A + r * 132 + (t & 1) * 64;
    float mx = -1e30f;
    for (int j = 0; j < 64; ++j) mx = fmaxf(mx, row[j]);
    mx = fmaxf(mx, __shfl_xor(mx, 1));
    float sum = 0.0f;
    for (int j = 0; j < 64; ++j) sum += __expf(row[j] - mx);
    sum += __shfl_xor(sum, 1);
    float inv = 1.0f / sum;
    unsigned short* outb = score_t + (size_t)bh * 16384 + r;
    const int e0 = (t & 1) * 64;
    for (int j = 0; j < 64; ++j)
      outb[(size_t)(e0 + j) * 128] = f2bf(__expf(row[j] - mx) * inv);
  }
}

// ---------------------------------------------------------------- launch
extern "C" void kernel_launch(void* const* d_in, const int* in_sizes, int n_in,
                              void* d_out, int out_size, void* d_ws, size_t ws_size,
                              hipStream_t stream) {
  const float* x     = (const float*)d_in[0];
  const float* alpha = (const float*)d_in[1];
  const float* Wq    = (const float*)d_in[2];
  const float* bq    = (const float*)d_in[3];
  const float* Wk    = (const float*)d_in[4];
  const float* bk    = (const float*)d_in[5];
  const float* Wv    = (const float*)d_in[6];
  const float* bv    = (const float*)d_in[7];
  const float* Wfc   = (const float*)d_in[8];
  const float* bfc   = (const float*)d_in[9];
  float* out = (float*)d_out;
  char* ws = (char*)d_ws;

  // workspace layout (302 MB):
  unsigned short* qkv     = (unsigned short*)(ws);                    // [16384][6144] bf16, 201326592 B
  unsigned short* xb      = (unsigned short*)(ws + 201326592);        // x bf16 / later out_attn, 67108864 B
  unsigned short* outat   = xb;                                       // aliased (x dead by then)
  char* regionB           = ws + 268435456;                           // wqkv_t OR kk/ktv/score_t
  unsigned short* wqkv_t  = (unsigned short*)regionB;                 // [6144][2048] bf16, 25165824 B
  float* kkbuf            = (float*)regionB;                          // [64][128][128] f32, 4194304 B
  float* ktvbuf           = (float*)(regionB + 4194304);              // 4194304 B
  unsigned short* score_t = (unsigned short*)(regionB + 8388608);     // [64][128][128] bf16, 2097152 B
  unsigned short* wfc_t   = (unsigned short*)(ws + 293601280);        // [2048][2048] bf16, 8388608 B
  float* bqkv             = (float*)(ws + 301989888);                 // [6144] f32

  transw_kernel<<<dim3(64, 64, 4), 256, 0, stream>>>(Wq, Wk, Wv, Wfc, wqkv_t, wfc_t);
  cast_x_kernel<<<32768, 256, 0, stream>>>(x, xb, 33554432L);
  bias_kernel<<<24, 256, 0, stream>>>(bq, bk, bv, bqkv);

  // fused QKV projection: [16384,2048] x [2048,6144] -> bf16 qkv
  gemm_bt<true, true><<<dim3(48, 128, 1), 256, 0, stream>>>(
      xb, 2048, wqkv_t, 2048, bqkv, qkv, 6144, 2048,
      0, 0, 0, 0, 0, 0, 1);

  hipMemsetAsync(kkbuf, 0, 8388608, stream);  // zero kk+ktv (contiguous)
  kkktv_kernel<<<dim3(64, 8, 1), 256, 0, stream>>>(qkv, kkbuf, ktvbuf);
  inv_softmax_kernel<<<64, 256, 0, stream>>>(kkbuf, ktvbuf, alpha, score_t);

  // out_attn[b,s,(h d)] = q[b,h] @ score[b,h] : batched over z=bh, K=128
  gemm_bt<true, false><<<dim3(1, 32, 64), 256, 0, stream>>>(
      qkv, 6144, score_t, 128, nullptr, outat, 2048, 128,
      25165824L, 128L,      // A: q rows b*4096.., col h*128
      262144L, 16384L,      // B: score_t per bh
      8388608L, 128L,       // C: out_attn rows b*4096.., col h*128
      16);

  // final: out_attn @ Wfc + bfc -> fp32 d_out
  gemm_bt<false, true><<<dim3(16, 128, 1), 256, 0, stream>>>(
      outat, 2048, wfc_t, 2048, bfc, out, 2048, 2048,
      0, 0, 0, 0, 0, 0, 1);
}

// Round 2
// 1104.905 us; speedup vs baseline: 1.5171x; 1.5171x over previous
//
#include <hip/hip_runtime.h>
#include <hip/hip_bf16.h>

// Shapes: B=4, S=4096, E=2048, NH=16, HD=128.  ST = B*S = 16384 rows.
// Layouts:
//   qbuf [16384][2048] bf16  (q projection)
//   Kt,Vt [64 bh][128 d][4096 s] bf16  (k/v projections, transposed per head)
//   kk,ktv [64 bh][128][128] f32 ; score_t [64 bh][128 e][128 d] bf16

typedef __attribute__((ext_vector_type(4))) float  f32x4;
typedef __attribute__((ext_vector_type(8))) short  s16x8;

__device__ __forceinline__ unsigned short f2bf(float f) {
  unsigned u = __float_as_uint(f);
  unsigned r = (u + 0x7FFFu + ((u >> 16) & 1u)) >> 16;   // RNE
  return (unsigned short)r;
}
__device__ __forceinline__ float bf2f(unsigned short u) {
  return __uint_as_float(((unsigned)u) << 16);
}

// async global->LDS, 16B per lane. LDS dest must be wave-uniform base + lane*16.
__device__ __forceinline__ void gld16(const void* g, void* l) {
  __builtin_amdgcn_global_load_lds(
      (const __attribute__((address_space(1))) unsigned int*)g,
      (__attribute__((address_space(3))) unsigned int*)l,
      16, 0, 0);
}

// ---------------------------------------------------------------- prep kernels
__global__ void cast_x_kernel(const float* __restrict__ x,
                              unsigned short* __restrict__ xb, long n) {
  long i = ((long)blockIdx.x * blockDim.x + threadIdx.x) * 4;
  if (i < n) {
    float4 v = *(const float4*)(x + i);
    ushort4 o;
    o.x = f2bf(v.x); o.y = f2bf(v.y); o.z = f2bf(v.z); o.w = f2bf(v.w);
    *(ushort4*)(xb + i) = o;
  }
}

// Wt[n][k] = W[k][n] as bf16. z picks Wq/Wk/Wv -> wqkv_t rows z*2048.., z=3 -> wfc_t.
__global__ void transw_kernel(const float* __restrict__ Wq, const float* __restrict__ Wk,
                              const float* __restrict__ Wv, const float* __restrict__ Wfc,
                              unsigned short* __restrict__ wqkv_t,
                              unsigned short* __restrict__ wfc_t) {
  __shared__ float tile[32][33];
  int z = blockIdx.z;
  const float* W = (z == 0) ? Wq : (z == 1) ? Wk : (z == 2) ? Wv : Wfc;
  unsigned short* dst = (z < 3) ? (wqkv_t + (size_t)z * 2048 * 2048) : wfc_t;
  int x0 = blockIdx.x * 32, y0 = blockIdx.y * 32;
  int tx = threadIdx.x & 31, ty = threadIdx.x >> 5;  // 256 thr: ty 0..7
#pragma unroll
  for (int r = 0; r < 4; ++r)
    tile[ty + r * 8][tx] = W[(size_t)(y0 + ty + r * 8) * 2048 + x0 + tx];
  __syncthreads();
#pragma unroll
  for (int r = 0; r < 4; ++r)
    dst[(size_t)(x0 + ty + r * 8) * 2048 + y0 + tx] = f2bf(tile[tx][ty + r * 8]);
}

__global__ void bias_kernel(const float* __restrict__ bq, const float* __restrict__ bk,
                            const float* __restrict__ bv, float* __restrict__ bqkv) {
  int i = blockIdx.x * 256 + threadIdx.x;  // 6144
  bqkv[i] = (i < 2048) ? bq[i] : (i < 4096) ? bk[i - 2048] : bv[i - 4096];
}

// ---------------------------------------------------------------- QKV GEMM
// C[16384,6144] = xb[16384,2048] * wqkv_t^T (+bias). 128x128 tile, BK=64.
// Epilogue routes by region: q -> qbuf row-major; k/v -> Kt/Vt TRANSPOSED
// per head ([bh][d][s]), as 8B ushort4 runs (4 row-consecutive acc values).
__global__ __launch_bounds__(256, 2)
void qkv_gemm(const unsigned short* __restrict__ A,
              const unsigned short* __restrict__ Bw,
              const float* __restrict__ bias,
              unsigned short* __restrict__ qbuf,
              unsigned short* __restrict__ Kt,
              unsigned short* __restrict__ Vt) {
  __shared__ __align__(16) unsigned short As[128 * 64];
  __shared__ __align__(16) unsigned short Bs[128 * 64];
  const int t = threadIdx.x;
  const int lane = t & 63;
  const int w = t >> 6;
  const int wr = (w >> 1) * 64, wc = (w & 1) * 64;
  const int l15 = lane & 15, lq = lane >> 4;
  const unsigned short* Ab = A + (size_t)blockIdx.y * 128 * 2048;
  const unsigned short* Bb = Bw + (size_t)blockIdx.x * 128 * 2048;

  f32x4 acc[4][4] = {};
  const int srow = t >> 3, scol = (t & 7) * 8;

  for (int kt = 0; kt < 32; ++kt) {
    const unsigned short* Ag = Ab + kt * 64 + (size_t)srow * 2048 + scol;
    const unsigned short* Bg = Bb + kt * 64 + (size_t)srow * 2048 + scol;
    __syncthreads();
#pragma unroll
    for (int i = 0; i < 4; ++i) {
      gld16(Ag + (size_t)(32 * i) * 2048, As + t * 8 + i * 2048);
      gld16(Bg + (size_t)(32 * i) * 2048, Bs + t * 8 + i * 2048);
    }
    __syncthreads();
#pragma unroll
    for (int ks = 0; ks < 2; ++ks) {
      s16x8 af[4], bf[4];
#pragma unroll
      for (int i = 0; i < 4; ++i) {
        af[i] = *(const s16x8*)(As + (wr + i * 16 + l15) * 64 + ks * 32 + lq * 8);
        bf[i] = *(const s16x8*)(Bs + (wc + i * 16 + l15) * 64 + ks * 32 + lq * 8);
      }
#pragma unroll
      for (int i = 0; i < 4; ++i)
#pragma unroll
        for (int j = 0; j < 4; ++j)
          acc[i][j] = __builtin_amdgcn_mfma_f32_16x16x32_bf16(af[i], bf[j], acc[i][j], 0, 0, 0);
    }
  }
  const int row0 = blockIdx.y * 128 + wr + lq * 4;
  const int col0 = blockIdx.x * 128 + wc + l15;
  const int region = blockIdx.x >> 4;  // 0=q, 1=k, 2=v
  if (region == 0) {
#pragma unroll
    for (int j = 0; j < 4; ++j) {
      int col = col0 + j * 16;
      float bv = bias[col];
#pragma unroll
      for (int i = 0; i < 4; ++i)
#pragma unroll
        for (int r = 0; r < 4; ++r)
          qbuf[(size_t)(row0 + i * 16 + r) * 2048 + col] = f2bf(acc[i][j][r] + bv);
    }
  } else {
    unsigned short* T = (region == 1) ? Kt : Vt;
#pragma unroll
    for (int j = 0; j < 4; ++j) {
      int col = col0 + j * 16;
      float bv = bias[col];
      int d = col & 127;
      int h = (col >> 7) & 15;
#pragma unroll
      for (int i = 0; i < 4; ++i) {
        int row = row0 + i * 16;
        int b = row >> 12, s = row & 4095;
        ushort4 u;
        u.x = f2bf(acc[i][j][0] + bv);
        u.y = f2bf(acc[i][j][1] + bv);
        u.z = f2bf(acc[i][j][2] + bv);
        u.w = f2bf(acc[i][j][3] + bv);
        *(ushort4*)(T + (size_t)(b * 16 + h) * 524288 + (size_t)d * 4096 + s) = u;
      }
    }
  }
}

// ---------------------------------------------------------------- K^T K, K^T V (MFMA)
// Per z: bh = z&63, op = (z>>6)&1 (0:kk, 1:ktv), split = z>>7 (K-split of 1024).
// C[128,128] (+=) A[128,1024-slice] * B^T, fp32 atomicAdd epilogue.
__global__ __launch_bounds__(256, 2)
void kk_gemm(const unsigned short* __restrict__ Kt,
             const unsigned short* __restrict__ Vt,
             float* __restrict__ kk, float* __restrict__ ktv) {
  __shared__ __align__(16) unsigned short As[128 * 64];
  __shared__ __align__(16) unsigned short Bs[128 * 64];
  const int t = threadIdx.x;
  const int lane = t & 63;
  const int w = t >> 6;
  const int wr = (w >> 1) * 64, wc = (w & 1) * 64;
  const int l15 = lane & 15, lq = lane >> 4;
  const int bh = blockIdx.z & 63;
  const int op = (blockIdx.z >> 6) & 1;
  const int split = blockIdx.z >> 7;
  const unsigned short* Ab = Kt + (size_t)bh * 524288 + split * 1024;
  const unsigned short* Bb = (op ? Vt : Kt) + (size_t)bh * 524288 + split * 1024;
  float* C = (op ? ktv : kk) + (size_t)bh * 16384;

  f32x4 acc[4][4] = {};
  const int srow = t >> 3, scol = (t & 7) * 8;

  for (int kt = 0; kt < 16; ++kt) {
    const unsigned short* Ag = Ab + kt * 64 + (size_t)srow * 4096 + scol;
    const unsigned short* Bg = Bb + kt * 64 + (size_t)srow * 4096 + scol;
    __syncthreads();
#pragma unroll
    for (int i = 0; i < 4; ++i) {
      gld16(Ag + (size_t)(32 * i) * 4096, As + t * 8 + i * 2048);
      gld16(Bg + (size_t)(32 * i) * 4096, Bs + t * 8 + i * 2048);
    }
    __syncthreads();
#pragma unroll
    for (int ks = 0; ks < 2; ++ks) {
      s16x8 af[4], bf[4];
#pragma unroll
      for (int i = 0; i < 4; ++i) {
        af[i] = *(const s16x8*)(As + (wr + i * 16 + l15) * 64 + ks * 32 + lq * 8);
        bf[i] = *(const s16x8*)(Bs + (wc + i * 16 + l15) * 64 + ks * 32 + lq * 8);
      }
#pragma unroll
      for (int i = 0; i < 4; ++i)
#pragma unroll
        for (int j = 0; j < 4; ++j)
          acc[i][j] = __builtin_amdgcn_mfma_f32_16x16x32_bf16(af[i], bf[j], acc[i][j], 0, 0, 0);
    }
  }
  const int row0 = wr + lq * 4;
  const int col0 = wc + l15;
#pragma unroll
  for (int j = 0; j < 4; ++j)
#pragma unroll
    for (int i = 0; i < 4; ++i)
#pragma unroll
      for (int r = 0; r < 4; ++r)
        atomicAdd(&C[(row0 + i * 16 + r) * 128 + col0 + j * 16], acc[i][j][r]);
}

// ---------------------------------------------------------------- generic GEMM
// C[M,N] = A[M,K] * B^T[N,K] (+bias). Used for q@score and final FC.
template <bool OUT_BF16, bool HAS_BIAS>
__global__ __launch_bounds__(256, 2)
void gemm_bt(const unsigned short* __restrict__ A, int lda,
             const unsigned short* __restrict__ B, int ldb,
             const float* __restrict__ bias,
             void* __restrict__ C, int ldc, int K,
             long sAb, long sAh, long sBb, long sBh, long sCb, long sCh,
             int nhmod) {
  __shared__ __align__(16) unsigned short As[128 * 64];
  __shared__ __align__(16) unsigned short Bs[128 * 64];
  const int t = threadIdx.x;
  const int lane = t & 63;
  const int w = t >> 6;
  const int wr = (w >> 1) * 64, wc = (w & 1) * 64;
  const int l15 = lane & 15, lq = lane >> 4;
  const int zb = blockIdx.z / nhmod, zh = blockIdx.z - zb * nhmod;
  const unsigned short* Ab = A + zb * sAb + zh * sAh + (size_t)blockIdx.y * 128 * lda;
  const unsigned short* Bb = B + zb * sBb + zh * sBh + (size_t)blockIdx.x * 128 * ldb;

  f32x4 acc[4][4] = {};
  const int nk = K >> 6;
  const int srow = t >> 3, scol = (t & 7) * 8;

  for (int kt = 0; kt < nk; ++kt) {
    const unsigned short* Ag = Ab + kt * 64 + (size_t)srow * lda + scol;
    const unsigned short* Bg = Bb + kt * 64 + (size_t)srow * ldb + scol;
    __syncthreads();
#pragma unroll
    for (int i = 0; i < 4; ++i) {
      gld16(Ag + (size_t)(32 * i) * lda, As + t * 8 + i * 2048);
      gld16(Bg + (size_t)(32 * i) * ldb, Bs + t * 8 + i * 2048);
    }
    __syncthreads();
#pragma unroll
    for (int ks = 0; ks < 2; ++ks) {
      s16x8 af[4], bf[4];
#pragma unroll
      for (int i = 0; i < 4; ++i) {
        af[i] = *(const s16x8*)(As + (wr + i * 16 + l15) * 64 + ks * 32 + lq * 8);
        bf[i] = *(const s16x8*)(Bs + (wc + i * 16 + l15) * 64 + ks * 32 + lq * 8);
      }
#pragma unroll
      for (int i = 0; i < 4; ++i)
#pragma unroll
        for (int j = 0; j < 4; ++j)
          acc[i][j] = __builtin_amdgcn_mfma_f32_16x16x32_bf16(af[i], bf[j], acc[i][j], 0, 0, 0);
    }
  }
  const long Cbase = zb * sCb + zh * sCh;
  const long row0 = (long)blockIdx.y * 128 + wr + lq * 4;
  const long col0 = (long)blockIdx.x * 128 + wc + l15;
#pragma unroll
  for (int j = 0; j < 4; ++j) {
    long col = col0 + j * 16;
    float bv = HAS_BIAS ? bias[col] : 0.0f;
#pragma unroll
    for (int i = 0; i < 4; ++i)
#pragma unroll
      for (int r = 0; r < 4; ++r) {
        float v = acc[i][j][r] + bv;
        long idx = Cbase + (row0 + i * 16 + r) * (long)ldc + col;
        if (OUT_BF16) ((unsigned short*)C)[idx] = f2bf(v);
        else          ((float*)C)[idx] = v;
      }
  }
}

// ------------------------------------------- inverse(alpha I + K^TK) @ K^TV, softmax
__global__ __launch_bounds__(256, 1)
void inv_softmax_kernel(const float* __restrict__ kk, const float* __restrict__ ktv,
                        const float* __restrict__ alphap,
                        unsigned short* __restrict__ score_t) {
  __shared__ __align__(16) float A[128 * 132];     // row stride 132 floats
  __shared__ __align__(16) float rowbuf[2][132];
  __shared__ __align__(16) float colbuf[2][132];
  const int bh = blockIdx.x, t = threadIdx.x;
  const float* kkb = kk + (size_t)bh * 16384;
  const float* tvb = ktv + (size_t)bh * 16384;
  const float al = alphap[0];

  for (int i = t; i < 16384; i += 256) {
    int r = i >> 7, c = i & 127;
    A[r * 132 + c] = kkb[i] + ((r == c) ? al : 0.0f);
  }
  __syncthreads();
  if (t < 128) { rowbuf[0][t] = A[t]; colbuf[0][t] = A[t * 132]; }
  __syncthreads();

  const int i2 = t >> 1, half = t & 1;
  const int jb = half * 64;
  for (int k = 0; k < 128; ++k) {
    const float* rb = rowbuf[k & 1];
    float piv = rb[k];
    float d = 1.0f / piv;
    float c = colbuf[k & 1][i2];
    bool isPivRow = (i2 == k);
    float cd = isPivRow ? 0.0f : c * d;
    float scale = isPivRow ? d : 1.0f;
    float* Arow = A + i2 * 132 + jb;
    const float* rbh = rb + jb;
#pragma unroll
    for (int jj = 0; jj < 16; ++jj) {
      float4 r4 = *(const float4*)(rbh + jj * 4);
      float4 v = *(float4*)(Arow + jj * 4);
      v.x = v.x * scale - cd * r4.x;
      v.y = v.y * scale - cd * r4.y;
      v.z = v.z * scale - cd * r4.z;
      v.w = v.w * scale - cd * r4.w;
      *(float4*)(Arow + jj * 4) = v;
    }
    if ((k >> 6) == half) {
      if (!isPivRow) A[i2 * 132 + k] = -c * d;
      else           A[k * 132 + k] = d;
    }
    __syncthreads();
    if (t < 128 && k < 127) {
      rowbuf[(k + 1) & 1][t] = A[(k + 1) * 132 + t];
      colbuf[(k + 1) & 1][t] = A[t * 132 + (k + 1)];
    }
    __syncthreads();
  }

  const int ty2 = t >> 4, tx2 = t & 15;
  float X[8][8] = {};
  for (int f = 0; f < 128; ++f) {
    float av[8];
#pragma unroll
    for (int i = 0; i < 8; ++i) av[i] = A[(ty2 * 8 + i) * 132 + f];
    float4 b0 = *(const float4*)(tvb + f * 128 + tx2 * 8);
    float4 b1 = *(const float4*)(tvb + f * 128 + tx2 * 8 + 4);
#pragma unroll
    for (int i = 0; i < 8; ++i) {
      X[i][0] = fmaf(av[i], b0.x, X[i][0]); X[i][1] = fmaf(av[i], b0.y, X[i][1]);
      X[i][2] = fmaf(av[i], b0.z, X[i][2]); X[i][3] = fmaf(av[i], b0.w, X[i][3]);
      X[i][4] = fmaf(av[i], b1.x, X[i][4]); X[i][5] = fmaf(av[i], b1.y, X[i][5]);
      X[i][6] = fmaf(av[i], b1.z, X[i][6]); X[i][7] = fmaf(av[i], b1.w, X[i][7]);
    }
  }
  __syncthreads();
#pragma unroll
  for (int i = 0; i < 8; ++i) {
    *(float4*)(A + (ty2 * 8 + i) * 132 + tx2 * 8)     = make_float4(X[i][0], X[i][1], X[i][2], X[i][3]);
    *(float4*)(A + (ty2 * 8 + i) * 132 + tx2 * 8 + 4) = make_float4(X[i][4], X[i][5], X[i][6], X[i][7]);
  }
  __syncthreads();
  {
    const int r = t >> 1;
    const float* row = A + r * 132 + (t & 1) * 64;
    float mx = -1e30f;
    for (int j = 0; j < 64; ++j) mx = fmaxf(mx, row[j]);
    mx = fmaxf(mx, __shfl_xor(mx, 1));
    float sum = 0.0f;
    for (int j = 0; j < 64; ++j) sum += __expf(row[j] - mx);
    sum += __shfl_xor(sum, 1);
    float inv = 1.0f / sum;
    unsigned short* outb = score_t + (size_t)bh * 16384 + r;
    const int e0 = (t & 1) * 64;
    for (int j = 0; j < 64; ++j)
      outb[(size_t)(e0 + j) * 128] = f2bf(__expf(row[j] - mx) * inv);
  }
}

// ---------------------------------------------------------------- launch
extern "C" void kernel_launch(void* const* d_in, const int* in_sizes, int n_in,
                              void* d_out, int out_size, void* d_ws, size_t ws_size,
                              hipStream_t stream) {
  const float* x     = (const float*)d_in[0];
  const float* alpha = (const float*)d_in[1];
  const float* Wq    = (const float*)d_in[2];
  const float* bq    = (const float*)d_in[3];
  const float* Wk    = (const float*)d_in[4];
  const float* bk    = (const float*)d_in[5];
  const float* Wv    = (const float*)d_in[6];
  const float* bv    = (const float*)d_in[7];
  const float* Wfc   = (const float*)d_in[8];
  const float* bfc   = (const float*)d_in[9];
  float* out = (float*)d_out;
  char* ws = (char*)d_ws;

  // workspace layout (<= 302 MB, same budget that passed in R0):
  unsigned short* qbuf   = (unsigned short*)(ws);                    // 64MB  [16384][2048]
  unsigned short* Kt     = (unsigned short*)(ws + 67108864);         // 64MB  [64][128][4096]
  unsigned short* Vt     = (unsigned short*)(ws + 134217728);        // 64MB
  unsigned short* xb     = (unsigned short*)(ws + 201326592);        // 64MB  x bf16 (dead after qkv_gemm)
  float* kkbuf           = (float*)(ws + 201326592);                 // alias xb: 4MB
  float* ktvbuf          = (float*)(ws + 201326592 + 4194304);       // 4MB
  unsigned short* score_t= (unsigned short*)(ws + 201326592 + 8388608); // 2MB
  unsigned short* outat  = Kt;                                       // alias Kt (dead after kk_gemm)
  unsigned short* wqkv_t = (unsigned short*)(ws + 268435456);        // 24MB (dead after qkv_gemm)
  unsigned short* wfc_t  = (unsigned short*)(ws + 293601280);        // 8MB
  float* bqkv            = (float*)(ws + 301989888);                 // 24KB

  transw_kernel<<<dim3(64, 64, 4), 256, 0, stream>>>(Wq, Wk, Wv, Wfc, wqkv_t, wfc_t);
  cast_x_kernel<<<32768, 256, 0, stream>>>(x, xb, 33554432L);
  bias_kernel<<<24, 256, 0, stream>>>(bq, bk, bv, bqkv);

  // fused QKV projection; writes qbuf + transposed Kt/Vt
  qkv_gemm<<<dim3(48, 128, 1), 256, 0, stream>>>(xb, wqkv_t, bqkv, qbuf, Kt, Vt);

  // K^TK, K^TV via MFMA, split-K=4, atomic fp32 accumulate
  hipMemsetAsync(kkbuf, 0, 8388608, stream);  // kk+ktv contiguous
  kk_gemm<<<dim3(1, 1, 512), 256, 0, stream>>>(Kt, Vt, kkbuf, ktvbuf);

  inv_softmax_kernel<<<64, 256, 0, stream>>>(kkbuf, ktvbuf, alpha, score_t);

  // out_attn[b,s,(h d)] = q[b,h] @ score[b,h]^T-layout : batched over z=bh, K=128
  gemm_bt<true, false><<<dim3(1, 32, 64), 256, 0, stream>>>(
      qbuf, 2048, score_t, 128, nullptr, outat, 2048, 128,
      8388608L, 128L,       // A: qbuf rows b*4096.., col h*128
      262144L, 16384L,      // B: score_t per bh
      8388608L, 128L,       // C: out_attn rows b*4096.., col h*128
      16);

  // final: out_attn @ Wfc + bfc -> fp32 d_out
  gemm_bt<false, true><<<dim3(16, 128, 1), 256, 0, stream>>>(
      outat, 2048, wfc_t, 2048, bfc, out, 2048, 2048,
      0, 0, 0, 0, 0, 0, 1);
}

// Round 3
// 1036.870 us; speedup vs baseline: 1.6166x; 1.0656x over previous
//
#include <hip/hip_runtime.h>
#include <hip/hip_bf16.h>

// Shapes: B=4, S=4096, E=2048, NH=16, HD=128.  ST = B*S = 16384 rows.
// Layouts:
//   qbuf [16384][2048] bf16  (q projection)
//   Kt,Vt [64 bh][128 d][4096 s] bf16  (k/v projections, transposed per head)
//   kk,ktv [64 bh][128][128] f32 ; score_t [64 bh][128 e][128 d] bf16
//
// LDS bank-conflict fix (R3): tiles are stored with an XOR swizzle — within a
// 128B row, physical 16B chunk p holds logical chunk p ^ (row & 7). The
// global_load_lds source address (per-lane!) applies the permutation on the
// read side; fragment ds_read_b128 applies it on the LDS side. This spreads
// a wave's 64 fragment reads across all 32 banks (2-way, free) instead of
// 16-way on half the banks.

typedef __attribute__((ext_vector_type(4))) float  f32x4;
typedef __attribute__((ext_vector_type(8))) short  s16x8;

__device__ __forceinline__ unsigned short f2bf(float f) {
  unsigned u = __float_as_uint(f);
  unsigned r = (u + 0x7FFFu + ((u >> 16) & 1u)) >> 16;   // RNE
  return (unsigned short)r;
}
__device__ __forceinline__ float bf2f(unsigned short u) {
  return __uint_as_float(((unsigned)u) << 16);
}

// async global->LDS, 16B per lane. LDS dest must be wave-uniform base + lane*16.
__device__ __forceinline__ void gld16(const void* g, void* l) {
  __builtin_amdgcn_global_load_lds(
      (const __attribute__((address_space(1))) unsigned int*)g,
      (__attribute__((address_space(3))) unsigned int*)l,
      16, 0, 0);
}

// ---------------------------------------------------------------- prep kernels
__global__ void cast_x_kernel(const float* __restrict__ x,
                              unsigned short* __restrict__ xb, long n) {
  long i = ((long)blockIdx.x * blockDim.x + threadIdx.x) * 4;
  if (i < n) {
    float4 v = *(const float4*)(x + i);
    ushort4 o;
    o.x = f2bf(v.x); o.y = f2bf(v.y); o.z = f2bf(v.z); o.w = f2bf(v.w);
    *(ushort4*)(xb + i) = o;
  }
}

// Wt[n][k] = W[k][n] as bf16. z picks Wq/Wk/Wv -> wqkv_t rows z*2048.., z=3 -> wfc_t.
__global__ void transw_kernel(const float* __restrict__ Wq, const float* __restrict__ Wk,
                              const float* __restrict__ Wv, const float* __restrict__ Wfc,
                              unsigned short* __restrict__ wqkv_t,
                              unsigned short* __restrict__ wfc_t) {
  __shared__ float tile[32][33];
  int z = blockIdx.z;
  const float* W = (z == 0) ? Wq : (z == 1) ? Wk : (z == 2) ? Wv : Wfc;
  unsigned short* dst = (z < 3) ? (wqkv_t + (size_t)z * 2048 * 2048) : wfc_t;
  int x0 = blockIdx.x * 32, y0 = blockIdx.y * 32;
  int tx = threadIdx.x & 31, ty = threadIdx.x >> 5;  // 256 thr: ty 0..7
#pragma unroll
  for (int r = 0; r < 4; ++r)
    tile[ty + r * 8][tx] = W[(size_t)(y0 + ty + r * 8) * 2048 + x0 + tx];
  __syncthreads();
#pragma unroll
  for (int r = 0; r < 4; ++r)
    dst[(size_t)(x0 + ty + r * 8) * 2048 + y0 + tx] = f2bf(tile[tx][ty + r * 8]);
}

__global__ void bias_kernel(const float* __restrict__ bq, const float* __restrict__ bk,
                            const float* __restrict__ bv, float* __restrict__ bqkv) {
  int i = blockIdx.x * 256 + threadIdx.x;  // 6144
  bqkv[i] = (i < 2048) ? bq[i] : (i < 4096) ? bk[i - 2048] : bv[i - 4096];
}

// ---------------------------------------------------------------- QKV GEMM
__global__ __launch_bounds__(256, 2)
void qkv_gemm(const unsigned short* __restrict__ A,
              const unsigned short* __restrict__ Bw,
              const float* __restrict__ bias,
              unsigned short* __restrict__ qbuf,
              unsigned short* __restrict__ Kt,
              unsigned short* __restrict__ Vt) {
  __shared__ __align__(16) unsigned short As[128 * 64];
  __shared__ __align__(16) unsigned short Bs[128 * 64];
  const int t = threadIdx.x;
  const int lane = t & 63;
  const int w = t >> 6;
  const int wr = (w >> 1) * 64, wc = (w & 1) * 64;
  const int l15 = lane & 15, lq = lane >> 4;
  const int sxor = l15 & 7;
  const unsigned short* Ab = A + (size_t)blockIdx.y * 128 * 2048;
  const unsigned short* Bb = Bw + (size_t)blockIdx.x * 128 * 2048;

  f32x4 acc[4][4] = {};
  const int srow = t >> 3;
  const int scol = (((t & 7) ^ (srow & 7))) * 8;   // swizzled source chunk

  for (int kt = 0; kt < 32; ++kt) {
    const unsigned short* Ag = Ab + kt * 64 + (size_t)srow * 2048 + scol;
    const unsigned short* Bg = Bb + kt * 64 + (size_t)srow * 2048 + scol;
    __syncthreads();
#pragma unroll
    for (int i = 0; i < 4; ++i) {
      gld16(Ag + (size_t)(32 * i) * 2048, As + t * 8 + i * 2048);
      gld16(Bg + (size_t)(32 * i) * 2048, Bs + t * 8 + i * 2048);
    }
    __syncthreads();
#pragma unroll
    for (int ks = 0; ks < 2; ++ks) {
      const int ca = ((ks * 4 + lq) ^ sxor) * 8;
      s16x8 af[4], bf[4];
#pragma unroll
      for (int i = 0; i < 4; ++i) {
        af[i] = *(const s16x8*)(As + (wr + i * 16 + l15) * 64 + ca);
        bf[i] = *(const s16x8*)(Bs + (wc + i * 16 + l15) * 64 + ca);
      }
#pragma unroll
      for (int i = 0; i < 4; ++i)
#pragma unroll
        for (int j = 0; j < 4; ++j)
          acc[i][j] = __builtin_amdgcn_mfma_f32_16x16x32_bf16(af[i], bf[j], acc[i][j], 0, 0, 0);
    }
  }
  const int row0 = blockIdx.y * 128 + wr + lq * 4;
  const int col0 = blockIdx.x * 128 + wc + l15;
  const int region = blockIdx.x >> 4;  // 0=q, 1=k, 2=v
  if (region == 0) {
#pragma unroll
    for (int j = 0; j < 4; ++j) {
      int col = col0 + j * 16;
      float bv = bias[col];
#pragma unroll
      for (int i = 0; i < 4; ++i)
#pragma unroll
        for (int r = 0; r < 4; ++r)
          qbuf[(size_t)(row0 + i * 16 + r) * 2048 + col] = f2bf(acc[i][j][r] + bv);
    }
  } else {
    unsigned short* T = (region == 1) ? Kt : Vt;
#pragma unroll
    for (int j = 0; j < 4; ++j) {
      int col = col0 + j * 16;
      float bv = bias[col];
      int d = col & 127;
      int h = (col >> 7) & 15;
#pragma unroll
      for (int i = 0; i < 4; ++i) {
        int row = row0 + i * 16;
        int b = row >> 12, s = row & 4095;
        ushort4 u;
        u.x = f2bf(acc[i][j][0] + bv);
        u.y = f2bf(acc[i][j][1] + bv);
        u.z = f2bf(acc[i][j][2] + bv);
        u.w = f2bf(acc[i][j][3] + bv);
        *(ushort4*)(T + (size_t)(b * 16 + h) * 524288 + (size_t)d * 4096 + s) = u;
      }
    }
  }
}

// ---------------------------------------------------------------- K^T K, K^T V (MFMA)
// Per z: bh = z&63, op = (z>>6)&1 (0:kk, 1:ktv), split = z>>7 (K-split of 1024).
__global__ __launch_bounds__(256, 2)
void kk_gemm(const unsigned short* __restrict__ Kt,
             const unsigned short* __restrict__ Vt,
             float* __restrict__ kk, float* __restrict__ ktv) {
  __shared__ __align__(16) unsigned short As[128 * 64];
  __shared__ __align__(16) unsigned short Bs[128 * 64];
  const int t = threadIdx.x;
  const int lane = t & 63;
  const int w = t >> 6;
  const int wr = (w >> 1) * 64, wc = (w & 1) * 64;
  const int l15 = lane & 15, lq = lane >> 4;
  const int sxor = l15 & 7;
  const int bh = blockIdx.z & 63;
  const int op = (blockIdx.z >> 6) & 1;
  const int split = blockIdx.z >> 7;
  const unsigned short* Ab = Kt + (size_t)bh * 524288 + split * 1024;
  const unsigned short* Bb = (op ? Vt : Kt) + (size_t)bh * 524288 + split * 1024;
  float* C = (op ? ktv : kk) + (size_t)bh * 16384;

  f32x4 acc[4][4] = {};
  const int srow = t >> 3;
  const int scol = (((t & 7) ^ (srow & 7))) * 8;

  for (int kt = 0; kt < 16; ++kt) {
    const unsigned short* Ag = Ab + kt * 64 + (size_t)srow * 4096 + scol;
    const unsigned short* Bg = Bb + kt * 64 + (size_t)srow * 4096 + scol;
    __syncthreads();
#pragma unroll
    for (int i = 0; i < 4; ++i) {
      gld16(Ag + (size_t)(32 * i) * 4096, As + t * 8 + i * 2048);
      gld16(Bg + (size_t)(32 * i) * 4096, Bs + t * 8 + i * 2048);
    }
    __syncthreads();
#pragma unroll
    for (int ks = 0; ks < 2; ++ks) {
      const int ca = ((ks * 4 + lq) ^ sxor) * 8;
      s16x8 af[4], bf[4];
#pragma unroll
      for (int i = 0; i < 4; ++i) {
        af[i] = *(const s16x8*)(As + (wr + i * 16 + l15) * 64 + ca);
        bf[i] = *(const s16x8*)(Bs + (wc + i * 16 + l15) * 64 + ca);
      }
#pragma unroll
      for (int i = 0; i < 4; ++i)
#pragma unroll
        for (int j = 0; j < 4; ++j)
          acc[i][j] = __builtin_amdgcn_mfma_f32_16x16x32_bf16(af[i], bf[j], acc[i][j], 0, 0, 0);
    }
  }
  const int row0 = wr + lq * 4;
  const int col0 = wc + l15;
#pragma unroll
  for (int j = 0; j < 4; ++j)
#pragma unroll
    for (int i = 0; i < 4; ++i)
#pragma unroll
      for (int r = 0; r < 4; ++r)
        atomicAdd(&C[(row0 + i * 16 + r) * 128 + col0 + j * 16], acc[i][j][r]);
}

// ---------------------------------------------------------------- generic GEMM
// C[M,N] = A[M,K] * B^T[N,K] (+bias). Used for q@score and final FC.
template <bool OUT_BF16, bool HAS_BIAS>
__global__ __launch_bounds__(256, 2)
void gemm_bt(const unsigned short* __restrict__ A, int lda,
             const unsigned short* __restrict__ B, int ldb,
             const float* __restrict__ bias,
             void* __restrict__ C, int ldc, int K,
             long sAb, long sAh, long sBb, long sBh, long sCb, long sCh,
             int nhmod) {
  __shared__ __align__(16) unsigned short As[128 * 64];
  __shared__ __align__(16) unsigned short Bs[128 * 64];
  const int t = threadIdx.x;
  const int lane = t & 63;
  const int w = t >> 6;
  const int wr = (w >> 1) * 64, wc = (w & 1) * 64;
  const int l15 = lane & 15, lq = lane >> 4;
  const int sxor = l15 & 7;
  const int zb = blockIdx.z / nhmod, zh = blockIdx.z - zb * nhmod;
  const unsigned short* Ab = A + zb * sAb + zh * sAh + (size_t)blockIdx.y * 128 * lda;
  const unsigned short* Bb = B + zb * sBb + zh * sBh + (size_t)blockIdx.x * 128 * ldb;

  f32x4 acc[4][4] = {};
  const int nk = K >> 6;
  const int srow = t >> 3;
  const int scol = (((t & 7) ^ (srow & 7))) * 8;

  for (int kt = 0; kt < nk; ++kt) {
    const unsigned short* Ag = Ab + kt * 64 + (size_t)srow * lda + scol;
    const unsigned short* Bg = Bb + kt * 64 + (size_t)srow * ldb + scol;
    __syncthreads();
#pragma unroll
    for (int i = 0; i < 4; ++i) {
      gld16(Ag + (size_t)(32 * i) * lda, As + t * 8 + i * 2048);
      gld16(Bg + (size_t)(32 * i) * ldb, Bs + t * 8 + i * 2048);
    }
    __syncthreads();
#pragma unroll
    for (int ks = 0; ks < 2; ++ks) {
      const int ca = ((ks * 4 + lq) ^ sxor) * 8;
      s16x8 af[4], bf[4];
#pragma unroll
      for (int i = 0; i < 4; ++i) {
        af[i] = *(const s16x8*)(As + (wr + i * 16 + l15) * 64 + ca);
        bf[i] = *(const s16x8*)(Bs + (wc + i * 16 + l15) * 64 + ca);
      }
#pragma unroll
      for (int i = 0; i < 4; ++i)
#pragma unroll
        for (int j = 0; j < 4; ++j)
          acc[i][j] = __builtin_amdgcn_mfma_f32_16x16x32_bf16(af[i], bf[j], acc[i][j], 0, 0, 0);
    }
  }
  const long Cbase = zb * sCb + zh * sCh;
  const long row0 = (long)blockIdx.y * 128 + wr + lq * 4;
  const long col0 = (long)blockIdx.x * 128 + wc + l15;
#pragma unroll
  for (int j = 0; j < 4; ++j) {
    long col = col0 + j * 16;
    float bv = HAS_BIAS ? bias[col] : 0.0f;
#pragma unroll
    for (int i = 0; i < 4; ++i)
#pragma unroll
      for (int r = 0; r < 4; ++r) {
        float v = acc[i][j][r] + bv;
        long idx = Cbase + (row0 + i * 16 + r) * (long)ldc + col;
        if (OUT_BF16) ((unsigned short*)C)[idx] = f2bf(v);
        else          ((float*)C)[idx] = v;
      }
  }
}

// ------------------------------------------- inverse(alpha I + K^TK) @ K^TV, softmax
__global__ __launch_bounds__(256, 1)
void inv_softmax_kernel(const float* __restrict__ kk, const float* __restrict__ ktv,
                        const float* __restrict__ alphap,
                        unsigned short* __restrict__ score_t) {
  __shared__ __align__(16) float A[128 * 132];     // row stride 132 floats
  __shared__ __align__(16) float rowbuf[2][132];
  __shared__ __align__(16) float colbuf[2][132];
  const int bh = blockIdx.x, t = threadIdx.x;
  const float* kkb = kk + (size_t)bh * 16384;
  const float* tvb = ktv + (size_t)bh * 16384;
  const float al = alphap[0];

  for (int i = t; i < 16384; i += 256) {
    int r = i >> 7, c = i & 127;
    A[r * 132 + c] = kkb[i] + ((r == c) ? al : 0.0f);
  }
  __syncthreads();
  if (t < 128) { rowbuf[0][t] = A[t]; colbuf[0][t] = A[t * 132]; }
  __syncthreads();

  const int i2 = t >> 1, half = t & 1;
  const int jb = half * 64;
  for (int k = 0; k < 128; ++k) {
    const float* rb = rowbuf[k & 1];
    float piv = rb[k];
    float d = 1.0f / piv;
    float c = colbuf[k & 1][i2];
    bool isPivRow = (i2 == k);
    float cd = isPivRow ? 0.0f : c * d;
    float scale = isPivRow ? d : 1.0f;
    float* Arow = A + i2 * 132 + jb;
    const float* rbh = rb + jb;
#pragma unroll
    for (int jj = 0; jj < 16; ++jj) {
      float4 r4 = *(const float4*)(rbh + jj * 4);
      float4 v = *(float4*)(Arow + jj * 4);
      v.x = v.x * scale - cd * r4.x;
      v.y = v.y * scale - cd * r4.y;
      v.z = v.z * scale - cd * r4.z;
      v.w = v.w * scale - cd * r4.w;
      *(float4*)(Arow + jj * 4) = v;
    }
    if ((k >> 6) == half) {
      if (!isPivRow) A[i2 * 132 + k] = -c * d;
      else           A[k * 132 + k] = d;
    }
    __syncthreads();
    if (t < 128 && k < 127) {
      rowbuf[(k + 1) & 1][t] = A[(k + 1) * 132 + t];
      colbuf[(k + 1) & 1][t] = A[t * 132 + (k + 1)];
    }
    __syncthreads();
  }

  const int ty2 = t >> 4, tx2 = t & 15;
  float X[8][8] = {};
  for (int f = 0; f < 128; ++f) {
    float av[8];
#pragma unroll
    for (int i = 0; i < 8; ++i) av[i] = A[(ty2 * 8 + i) * 132 + f];
    float4 b0 = *(const float4*)(tvb + f * 128 + tx2 * 8);
    float4 b1 = *(const float4*)(tvb + f * 128 + tx2 * 8 + 4);
#pragma unroll
    for (int i = 0; i < 8; ++i) {
      X[i][0] = fmaf(av[i], b0.x, X[i][0]); X[i][1] = fmaf(av[i], b0.y, X[i][1]);
      X[i][2] = fmaf(av[i], b0.z, X[i][2]); X[i][3] = fmaf(av[i], b0.w, X[i][3]);
      X[i][4] = fmaf(av[i], b1.x, X[i][4]); X[i][5] = fmaf(av[i], b1.y, X[i][5]);
      X[i][6] = fmaf(av[i], b1.z, X[i][6]); X[i][7] = fmaf(av[i], b1.w, X[i][7]);
    }
  }
  __syncthreads();
#pragma unroll
  for (int i = 0; i < 8; ++i) {
    *(float4*)(A + (ty2 * 8 + i) * 132 + tx2 * 8)     = make_float4(X[i][0], X[i][1], X[i][2], X[i][3]);
    *(float4*)(A + (ty2 * 8 + i) * 132 + tx2 * 8 + 4) = make_float4(X[i][4], X[i][5], X[i][6], X[i][7]);
  }
  __syncthreads();
  {
    const int r = t >> 1;
    const float* row = A + r * 132 + (t & 1) * 64;
    float mx = -1e30f;
    for (int j = 0; j < 64; ++j) mx = fmaxf(mx, row[j]);
    mx = fmaxf(mx, __shfl_xor(mx, 1));
    float sum = 0.0f;
    for (int j = 0; j < 64; ++j) sum += __expf(row[j] - mx);
    sum += __shfl_xor(sum, 1);
    float inv = 1.0f / sum;
    unsigned short* outb = score_t + (size_t)bh * 16384 + r;
    const int e0 = (t & 1) * 64;
    for (int j = 0; j < 64; ++j)
      outb[(size_t)(e0 + j) * 128] = f2bf(__expf(row[j] - mx) * inv);
  }
}

// ---------------------------------------------------------------- launch
extern "C" void kernel_launch(void* const* d_in, const int* in_sizes, int n_in,
                              void* d_out, int out_size, void* d_ws, size_t ws_size,
                              hipStream_t stream) {
  const float* x     = (const float*)d_in[0];
  const float* alpha = (const float*)d_in[1];
  const float* Wq    = (const float*)d_in[2];
  const float* bq    = (const float*)d_in[3];
  const float* Wk    = (const float*)d_in[4];
  const float* bk    = (const float*)d_in[5];
  const float* Wv    = (const float*)d_in[6];
  const float* bv    = (const float*)d_in[7];
  const float* Wfc   = (const float*)d_in[8];
  const float* bfc   = (const float*)d_in[9];
  float* out = (float*)d_out;
  char* ws = (char*)d_ws;

  unsigned short* qbuf   = (unsigned short*)(ws);                    // 64MB
  unsigned short* Kt     = (unsigned short*)(ws + 67108864);         // 64MB
  unsigned short* Vt     = (unsigned short*)(ws + 134217728);        // 64MB
  unsigned short* xb     = (unsigned short*)(ws + 201326592);        // 64MB (dead after qkv_gemm)
  float* kkbuf           = (float*)(ws + 201326592);                 // alias xb: 4MB
  float* ktvbuf          = (float*)(ws + 201326592 + 4194304);       // 4MB
  unsigned short* score_t= (unsigned short*)(ws + 201326592 + 8388608); // 2MB
  unsigned short* outat  = Kt;                                       // alias Kt (dead after kk_gemm)
  unsigned short* wqkv_t = (unsigned short*)(ws + 268435456);        // 24MB
  unsigned short* wfc_t  = (unsigned short*)(ws + 293601280);        // 8MB
  float* bqkv            = (float*)(ws + 301989888);                 // 24KB

  transw_kernel<<<dim3(64, 64, 4), 256, 0, stream>>>(Wq, Wk, Wv, Wfc, wqkv_t, wfc_t);
  cast_x_kernel<<<32768, 256, 0, stream>>>(x, xb, 33554432L);
  bias_kernel<<<24, 256, 0, stream>>>(bq, bk, bv, bqkv);

  // fused QKV projection; writes qbuf + transposed Kt/Vt
  qkv_gemm<<<dim3(48, 128, 1), 256, 0, stream>>>(xb, wqkv_t, bqkv, qbuf, Kt, Vt);

  // K^TK, K^TV via MFMA, split-K=4, atomic fp32 accumulate
  hipMemsetAsync(kkbuf, 0, 8388608, stream);  // kk+ktv contiguous
  kk_gemm<<<dim3(1, 1, 512), 256, 0, stream>>>(Kt, Vt, kkbuf, ktvbuf);

  inv_softmax_kernel<<<64, 256, 0, stream>>>(kkbuf, ktvbuf, alpha, score_t);

  // out_attn[b,s,(h d)] = q[b,h] @ score[b,h]^T-layout : batched over z=bh, K=128
  gemm_bt<true, false><<<dim3(1, 32, 64), 256, 0, stream>>>(
      qbuf, 2048, score_t, 128, nullptr, outat, 2048, 128,
      8388608L, 128L,
      262144L, 16384L,
      8388608L, 128L,
      16);

  // final: out_attn @ Wfc + bfc -> fp32 d_out
  gemm_bt<false, true><<<dim3(16, 128, 1), 256, 0, stream>>>(
      outat, 2048, wfc_t, 2048, bfc, out, 2048, 2048,
      0, 0, 0, 0, 0, 0, 1);
}